// Round 2
// baseline (147.798 us; speedup 1.0000x reference)
//
#include <hip/hip_runtime.h>
#include <hip/hip_bf16.h>

// ---------------------------------------------------------------------------
// LayerNormGRUCell: B=16384, I=H=512
//   G = [x@W_i2h.T | h@W_h2h.T | x@W_hatW.T | h@W_hatU.T]  (16384 x 3072)
//   then per-row: LN segments + gates + tanh + lerp -> h_t (16384 x 512 fp32)
// ws layout (bf16 elements):
//   xb   @ 0         (16384*512)
//   hb   @ 8388608   (16384*512)
//   Wcat @ 16777216  (3072*512)   rows: [W_i2h;W_h2h;W_hatW;W_hatU]
//   Gb   @ 18350080  (16384*3072)
// total 68,681,728 bf16 = 137.4 MB
// ---------------------------------------------------------------------------

using f32x4 = __attribute__((ext_vector_type(4))) float;
using s16x8 = __attribute__((ext_vector_type(8))) short;

#define XB_OFF   0ull
#define HB_OFF   8388608ull
#define WB_OFF   16777216ull
#define GB_OFF   18350080ull

// vec4 segment boundaries for the convert kernel
#define CV_X_END   2097152ull                  // 16384*512/4
#define CV_H_END   4194304ull                  // + 16384*512/4
#define CV_W0_END  4325376ull                  // + 1024*512/4
#define CV_W1_END  4456448ull                  // + 1024*512/4
#define CV_W2_END  4521984ull                  // + 512*512/4
#define CV_W3_END  4587520ull                  // + 512*512/4  (grid*256 == this)

__device__ __forceinline__ void async_load16(const void* g, void* l) {
  __builtin_amdgcn_global_load_lds(
      (const __attribute__((address_space(1))) unsigned int*)g,
      (__attribute__((address_space(3))) unsigned int*)l, 16, 0, 0);
}

__device__ __forceinline__ float bfraw2f(unsigned short u) {
  union { unsigned int i; float f; } c;
  c.i = ((unsigned int)u) << 16;
  return c.f;
}

// -------------------------- fp32 -> bf16 conversion ------------------------
__global__ __launch_bounds__(256) void convert_kernel(
    const float* __restrict__ x, const float* __restrict__ h,
    const float* __restrict__ w0, const float* __restrict__ w1,
    const float* __restrict__ w2, const float* __restrict__ w3,
    __hip_bfloat16* __restrict__ ws)
{
  const size_t i = (size_t)blockIdx.x * 256 + threadIdx.x;  // vec4 index
  const float* src;
  __hip_bfloat16* dst;
  size_t o;
  if (i < CV_X_END)        { src = x;  dst = ws + XB_OFF;            o = i; }
  else if (i < CV_H_END)   { src = h;  dst = ws + HB_OFF;            o = i - CV_X_END; }
  else if (i < CV_W0_END)  { src = w0; dst = ws + WB_OFF;            o = i - CV_H_END; }
  else if (i < CV_W1_END)  { src = w1; dst = ws + WB_OFF + 524288;   o = i - CV_W0_END; }
  else if (i < CV_W2_END)  { src = w2; dst = ws + WB_OFF + 1048576;  o = i - CV_W1_END; }
  else                     { src = w3; dst = ws + WB_OFF + 1310720;  o = i - CV_W2_END; }
  const float4 v = *(const float4*)(src + 4 * o);
  __hip_bfloat16 t4[4] = {__float2bfloat16(v.x), __float2bfloat16(v.y),
                          __float2bfloat16(v.z), __float2bfloat16(v.w)};
  *(uint2*)(dst + 4 * o) = *(const uint2*)t4;
}

// -------------------------------- GEMM -------------------------------------
// C[m,n] = sum_k A[m,k] * W[n,k], both K-major (gemm_bt). 128x128 tile, BK=64,
// 4 waves (2x2), each wave 64x64 = 4x4 fragments of 16x16x32 bf16 MFMA.
__global__ __launch_bounds__(256) void gemm_kernel(
    const __hip_bfloat16* __restrict__ xb,
    const __hip_bfloat16* __restrict__ hb,
    const __hip_bfloat16* __restrict__ Wb,
    __hip_bfloat16* __restrict__ G)
{
  const int m0 = blockIdx.x * 128;
  const int n0 = blockIdx.y * 128;
  const int seg = n0 >> 9;  // 512-wide segments: 0,1,4 -> x ; 2,3,5 -> h
  const __hip_bfloat16* A = (seg < 2 || seg == 4) ? xb : hb;

  __shared__ __hip_bfloat16 As[128 * 64];
  __shared__ __hip_bfloat16 Bs[128 * 64];

  const int tid  = threadIdx.x;
  const int lane = tid & 63;
  const int wave = tid >> 6;
  const int wr = wave >> 1, wc = wave & 1;

  f32x4 acc[4][4];
#pragma unroll
  for (int i = 0; i < 4; ++i)
#pragma unroll
    for (int j = 0; j < 4; ++j) acc[i][j] = (f32x4){0.f, 0.f, 0.f, 0.f};

  const int srow = lane >> 3;          // row-within-chunk (8 rows per 1KB chunk)
  const int sb   = (lane & 7) * 16;    // byte offset within a 128B row
  const char* Abase = (const char*)A  + (size_t)m0 * 1024;  // row stride 512*2B
  const char* Bbase = (const char*)Wb + (size_t)n0 * 1024;

  for (int kt = 0; kt < 8; ++kt) {     // K = 512 = 8 * 64
    const int kbyte = kt * 128;
#pragma unroll
    for (int c = 0; c < 4; ++c) {
      const int chunk = wave * 4 + c;          // 16 chunks of 1KB per tile
      const int row = chunk * 8 + srow;
      async_load16(Abase + (size_t)row * 1024 + kbyte + sb,
                   (char*)As + chunk * 1024 + lane * 16);
      async_load16(Bbase + (size_t)row * 1024 + kbyte + sb,
                   (char*)Bs + chunk * 1024 + lane * 16);
    }
    asm volatile("s_waitcnt vmcnt(0)" ::: "memory");
    __syncthreads();
#pragma unroll
    for (int kk = 0; kk < 2; ++kk) {
      s16x8 a[4], b[4];
#pragma unroll
      for (int i = 0; i < 4; ++i) {
        a[i] = *(const s16x8*)((const char*)As +
                 (wr * 64 + i * 16 + (lane & 15)) * 128 + kk * 64 + (lane >> 4) * 16);
        b[i] = *(const s16x8*)((const char*)Bs +
                 (wc * 64 + i * 16 + (lane & 15)) * 128 + kk * 64 + (lane >> 4) * 16);
      }
#pragma unroll
      for (int i = 0; i < 4; ++i)
#pragma unroll
        for (int j = 0; j < 4; ++j)
          acc[i][j] = __builtin_amdgcn_mfma_f32_16x16x32_bf16(a[i], b[j], acc[i][j], 0, 0, 0);
    }
    __syncthreads();
  }

  // epilogue: D lane map: col = lane&15, row = (lane>>4)*4 + reg
#pragma unroll
  for (int i = 0; i < 4; ++i) {
    const int mb = m0 + wr * 64 + i * 16 + ((lane >> 4) << 2);
#pragma unroll
    for (int j = 0; j < 4; ++j) {
      const int nn = n0 + wc * 64 + j * 16 + (lane & 15);
#pragma unroll
      for (int r = 0; r < 4; ++r)
        G[(size_t)(mb + r) * 3072 + nn] = __float2bfloat16(acc[i][j][r]);
    }
  }
}

// ------------------------------ LN + gates ---------------------------------
__device__ __forceinline__ float4 block_red4(float4 v, float* red, int tid) {
#pragma unroll
  for (int off = 32; off; off >>= 1) {
    v.x += __shfl_down(v.x, off);
    v.y += __shfl_down(v.y, off);
    v.z += __shfl_down(v.z, off);
    v.w += __shfl_down(v.w, off);
  }
  __syncthreads();  // protect `red` against previous use
  if ((tid & 63) == 0) {
    const int w = tid >> 6;
    red[w * 4 + 0] = v.x; red[w * 4 + 1] = v.y;
    red[w * 4 + 2] = v.z; red[w * 4 + 3] = v.w;
  }
  __syncthreads();
  return make_float4(red[0] + red[4] + red[8]  + red[12],
                     red[1] + red[5] + red[9]  + red[13],
                     red[2] + red[6] + red[10] + red[14],
                     red[3] + red[7] + red[11] + red[15]);
}

__global__ __launch_bounds__(256) void ln_gate_kernel(
    const __hip_bfloat16* __restrict__ G, const float* __restrict__ h,
    const float* __restrict__ b0, const float* __restrict__ b1,
    const float* __restrict__ b2, const float* __restrict__ b3,
    float* __restrict__ out)
{
  const int row = blockIdx.x;
  const int t   = threadIdx.x;
  const unsigned short* g = (const unsigned short*)(G + (size_t)row * 3072);

  __shared__ float zr[1024];
  __shared__ float red[16];

  // segments 0 (i2h) and 1 (h2h): thread owns cols 4t..4t+3 of both
  float v0[4], v1[4];
  {
    const ushort4 u = *(const ushort4*)(g + 4 * t);
    const float4 b = *(const float4*)(b0 + 4 * t);
    v0[0] = bfraw2f(u.x) + b.x; v0[1] = bfraw2f(u.y) + b.y;
    v0[2] = bfraw2f(u.z) + b.z; v0[3] = bfraw2f(u.w) + b.w;
  }
  {
    const ushort4 u = *(const ushort4*)(g + 1024 + 4 * t);
    const float4 b = *(const float4*)(b1 + 4 * t);
    v1[0] = bfraw2f(u.x) + b.x; v1[1] = bfraw2f(u.y) + b.y;
    v1[2] = bfraw2f(u.z) + b.z; v1[3] = bfraw2f(u.w) + b.w;
  }
  float4 a;
  a.x = v0[0] + v0[1] + v0[2] + v0[3];
  a.y = v0[0]*v0[0] + v0[1]*v0[1] + v0[2]*v0[2] + v0[3]*v0[3];
  a.z = v1[0] + v1[1] + v1[2] + v1[3];
  a.w = v1[0]*v1[0] + v1[1]*v1[1] + v1[2]*v1[2] + v1[3]*v1[3];
  const float4 r01 = block_red4(a, red, t);
  const float mu0 = r01.x * (1.f / 1024.f);
  const float mu1 = r01.z * (1.f / 1024.f);
  const float rs0 = rsqrtf(r01.y * (1.f / 1024.f) - mu0 * mu0 + 1e-5f);
  const float rs1 = rsqrtf(r01.w * (1.f / 1024.f) - mu1 * mu1 + 1e-5f);

#pragma unroll
  for (int k = 0; k < 4; ++k) {
    const float pre = (v0[k] - mu0) * rs0 + (v1[k] - mu1) * rs1;
    zr[4 * t + k] = 1.f / (1.f + __expf(-pre));  // cols<512: z, cols>=512: r
  }

  // segments 2 (hat_a) and 3 (hat_b): thread owns cols 2t..2t+1
  float v2[2], v3[2];
  {
    const ushort2 u = *(const ushort2*)(g + 2048 + 2 * t);
    const float2 b = *(const float2*)(b2 + 2 * t);
    v2[0] = bfraw2f(u.x) + b.x; v2[1] = bfraw2f(u.y) + b.y;
  }
  {
    const ushort2 u = *(const ushort2*)(g + 2560 + 2 * t);
    const float2 b = *(const float2*)(b3 + 2 * t);
    v3[0] = bfraw2f(u.x) + b.x; v3[1] = bfraw2f(u.y) + b.y;
  }
  a.x = v2[0] + v2[1];
  a.y = v2[0]*v2[0] + v2[1]*v2[1];
  a.z = v3[0] + v3[1];
  a.w = v3[0]*v3[0] + v3[1]*v3[1];
  const float4 r23 = block_red4(a, red, t);  // syncs also publish zr[]
  const float mu2 = r23.x * (1.f / 512.f);
  const float mu3 = r23.z * (1.f / 512.f);
  const float rs2 = rsqrtf(r23.y * (1.f / 512.f) - mu2 * mu2 + 1e-5f);
  const float rs3 = rsqrtf(r23.w * (1.f / 512.f) - mu3 * mu3 + 1e-5f);

  const float2 hv = *(const float2*)(h + (size_t)row * 512 + 2 * t);
  float o[2];
#pragma unroll
  for (int k = 0; k < 2; ++k) {
    const int j = 2 * t + k;
    const float ha = (v2[k] - mu2) * rs2;
    const float hb = (v3[k] - mu3) * rs3;
    const float hhat = tanhf(ha + zr[512 + j] * hb);
    const float z = zr[j];
    const float hvk = (k == 0) ? hv.x : hv.y;
    o[k] = (1.f - z) * hvk + z * hhat;
  }
  *(float2*)(out + (size_t)row * 512 + 2 * t) = make_float2(o[0], o[1]);
}

// ------------------------------- launcher ----------------------------------
extern "C" void kernel_launch(void* const* d_in, const int* in_sizes, int n_in,
                              void* d_out, int out_size, void* d_ws, size_t ws_size,
                              hipStream_t stream) {
  (void)in_sizes; (void)n_in; (void)out_size; (void)ws_size;
  const float* x      = (const float*)d_in[0];
  const float* h      = (const float*)d_in[1];
  const float* W_i2h  = (const float*)d_in[2];
  const float* b_i2h  = (const float*)d_in[3];
  const float* W_h2h  = (const float*)d_in[4];
  const float* b_h2h  = (const float*)d_in[5];
  const float* W_hatW = (const float*)d_in[6];
  const float* b_hatW = (const float*)d_in[7];
  const float* W_hatU = (const float*)d_in[8];
  const float* b_hatU = (const float*)d_in[9];
  float* out = (float*)d_out;
  __hip_bfloat16* ws = (__hip_bfloat16*)d_ws;

  convert_kernel<<<17920, 256, 0, stream>>>(x, h, W_i2h, W_h2h, W_hatW, W_hatU, ws);
  gemm_kernel<<<dim3(128, 24), 256, 0, stream>>>(ws + XB_OFF, ws + HB_OFF,
                                                 ws + WB_OFF, ws + GB_OFF);
  ln_gate_kernel<<<16384, 256, 0, stream>>>(ws + GB_OFF, h, b_i2h, b_h2h,
                                            b_hatW, b_hatU, out);
}

// Round 3
// 136.038 us; speedup vs baseline: 1.0864x; 1.0864x over previous
//
#include <hip/hip_runtime.h>
#include <hip/hip_bf16.h>

// ---------------------------------------------------------------------------
// LayerNormGRUCell: B=16384, I=H=512
//   G = [x@W_i2h.T | h@W_h2h.T | x@W_hatW.T | h@W_hatU.T]  (16384 x 3072)
//   then per-row: LN segments + gates + tanh + lerp -> h_t (16384 x 512 fp32)
// ws layout (bf16 elements):
//   xb   @ 0         (16384*512)
//   hb   @ 8388608   (16384*512)
//   Wcat @ 16777216  (3072*512)   rows: [W_i2h;W_h2h;W_hatW;W_hatU]
//   Gb   @ 18350080  (16384*3072)
// ---------------------------------------------------------------------------

using f32x4 = __attribute__((ext_vector_type(4))) float;
using s16x8 = __attribute__((ext_vector_type(8))) short;

#define XB_OFF   0ull
#define HB_OFF   8388608ull
#define WB_OFF   16777216ull
#define GB_OFF   18350080ull

// vec4 segment boundaries for the convert kernel
#define CV_X_END   2097152ull
#define CV_H_END   4194304ull
#define CV_W0_END  4325376ull
#define CV_W1_END  4456448ull
#define CV_W2_END  4521984ull
#define CV_W3_END  4587520ull

__device__ __forceinline__ void async_load16(const void* g, void* l) {
  __builtin_amdgcn_global_load_lds(
      (const __attribute__((address_space(1))) unsigned int*)g,
      (__attribute__((address_space(3))) unsigned int*)l, 16, 0, 0);
}

__device__ __forceinline__ float bfraw2f(unsigned short u) {
  union { unsigned int i; float f; } c;
  c.i = ((unsigned int)u) << 16;
  return c.f;
}

// -------------------------- fp32 -> bf16 conversion ------------------------
__global__ __launch_bounds__(256) void convert_kernel(
    const float* __restrict__ x, const float* __restrict__ h,
    const float* __restrict__ w0, const float* __restrict__ w1,
    const float* __restrict__ w2, const float* __restrict__ w3,
    __hip_bfloat16* __restrict__ ws)
{
  const size_t i = (size_t)blockIdx.x * 256 + threadIdx.x;  // vec4 index
  const float* src;
  __hip_bfloat16* dst;
  size_t o;
  if (i < CV_X_END)        { src = x;  dst = ws + XB_OFF;            o = i; }
  else if (i < CV_H_END)   { src = h;  dst = ws + HB_OFF;            o = i - CV_X_END; }
  else if (i < CV_W0_END)  { src = w0; dst = ws + WB_OFF;            o = i - CV_H_END; }
  else if (i < CV_W1_END)  { src = w1; dst = ws + WB_OFF + 524288;   o = i - CV_W0_END; }
  else if (i < CV_W2_END)  { src = w2; dst = ws + WB_OFF + 1048576;  o = i - CV_W1_END; }
  else                     { src = w3; dst = ws + WB_OFF + 1310720;  o = i - CV_W2_END; }
  const float4 v = *(const float4*)(src + 4 * o);
  __hip_bfloat16 t4[4] = {__float2bfloat16(v.x), __float2bfloat16(v.y),
                          __float2bfloat16(v.z), __float2bfloat16(v.w)};
  *(uint2*)(dst + 4 * o) = *(const uint2*)t4;
}

// -------------------------------- GEMM -------------------------------------
// 256x256 tile, BK=32, 8 waves (2Mx4N), 4-slot LDS ring (128 KiB), counted
// vmcnt pipeline (T3+T4), XOR-swizzled LDS (T2), setprio around MFMA (T5),
// bijective XCD block swizzle (T1). C[m,n] = sum_k A[m,k]*W[n,k].
//
// LDS slot layout (per matrix): [256 rows][32 bf16 = 64 B], physical column
// byte cb holds global k-byte (cb ^ swz(row)), swz(row) = ((row>>1)&3)<<4.
// global_load_lds writes linearly (dest = chunkbase + lane*16); the source
// global address is pre-swizzled so LDS(row,cb) = G(row, cb ^ swz(row)).
// ds_read applies the same XOR -> round-trips to identity (rule 21).
// Read banks: lanes 0-15 read 16 rows, cb' = lk ^ swz(row): 8 distinct
// non-overlapping b128 bank groups x 2 rows = 2-way (free, m136).

#define SLOT_BYTES 16384   // 256*32*2
#define LDSB_OFF   65536   // 4 A slots

__device__ __forceinline__ void stage_mat(const char* base, char* slot,
                                          int koff, int wave, int lane) {
#pragma unroll
  for (int i = 0; i < 2; ++i) {
    const int c = wave * 2 + i;                       // 16-row chunk, 1024 B
    const int row = c * 16 + (lane >> 2);
    const int colb = ((lane & 3) * 16) ^ (((lane >> 3) & 3) << 4);  // pre-swz
    async_load16(base + (size_t)row * 1024 + koff + colb,
                 slot + c * 1024 + lane * 16);
  }
}

template <int VM>
__device__ __forceinline__ void wait_vm() {
  if constexpr (VM == 8)      asm volatile("s_waitcnt vmcnt(8)" ::: "memory");
  else if constexpr (VM == 4) asm volatile("s_waitcnt vmcnt(4)" ::: "memory");
  else                        asm volatile("s_waitcnt vmcnt(0)" ::: "memory");
}

template <int VM, bool STAGE>
__device__ __forceinline__ void ktile_step(
    int t, const char* Ab, const char* Bb, char* lds,
    int wave, int lane, int wm, int wn, f32x4 (&acc)[8][4])
{
  wait_vm<VM>();                       // counted: subtiles t+1,t+2 stay in flight
  __builtin_amdgcn_s_barrier();        // all threads drained their subtile-t loads
  char* slotA = lds + (t & 3) * SLOT_BYTES;
  char* slotB = lds + LDSB_OFF + (t & 3) * SLOT_BYTES;
  char* stA   = lds + ((t + 3) & 3) * SLOT_BYTES;           // == slot (t-1)&3:
  char* stB   = lds + LDSB_OFF + ((t + 3) & 3) * SLOT_BYTES; // reads done pre-barrier
  const int lk = (lane >> 4) * 16;
  const int lr = lane & 15;

  // ---- phase A: stage A(t+3) | read a0-3,b0-3 | 16 MFMA ----
  if (STAGE) stage_mat(Ab, stA, (t + 3) * 64, wave, lane);
  s16x8 a[4], b[4];
#pragma unroll
  for (int fn = 0; fn < 4; ++fn) {
    const int r = wn * 64 + fn * 16 + lr;
    b[fn] = *(const s16x8*)(slotB + r * 64 + (lk ^ (((r >> 1) & 3) << 4)));
  }
#pragma unroll
  for (int fm = 0; fm < 4; ++fm) {
    const int r = wm * 128 + fm * 16 + lr;
    a[fm] = *(const s16x8*)(slotA + r * 64 + (lk ^ (((r >> 1) & 3) << 4)));
  }
  __builtin_amdgcn_s_setprio(1);
#pragma unroll
  for (int fm = 0; fm < 4; ++fm)
#pragma unroll
    for (int fn = 0; fn < 4; ++fn)
      acc[fm][fn] = __builtin_amdgcn_mfma_f32_16x16x32_bf16(a[fm], b[fn], acc[fm][fn], 0, 0, 0);
  __builtin_amdgcn_s_setprio(0);

  // ---- phase B: stage B(t+3) | read a4-7 | 16 MFMA ----
  if (STAGE) stage_mat(Bb, stB, (t + 3) * 64, wave, lane);
#pragma unroll
  for (int fm = 0; fm < 4; ++fm) {
    const int r = wm * 128 + 64 + fm * 16 + lr;
    a[fm] = *(const s16x8*)(slotA + r * 64 + (lk ^ (((r >> 1) & 3) << 4)));
  }
  __builtin_amdgcn_s_setprio(1);
#pragma unroll
  for (int fm = 0; fm < 4; ++fm)
#pragma unroll
    for (int fn = 0; fn < 4; ++fn)
      acc[4 + fm][fn] = __builtin_amdgcn_mfma_f32_16x16x32_bf16(a[fm], b[fn], acc[4 + fm][fn], 0, 0, 0);
  __builtin_amdgcn_s_setprio(0);
}

__global__ __launch_bounds__(512, 2) void gemm_kernel(
    const __hip_bfloat16* __restrict__ xb,
    const __hip_bfloat16* __restrict__ hb,
    const __hip_bfloat16* __restrict__ Wb,
    __hip_bfloat16* __restrict__ G)
{
  // T1: bijective XCD swizzle; nwg=768, 768%8==0, chunk=96 wgs/XCD.
  // n-tile fastest within a chunk -> consecutive blocks share the A panel.
  const int bid = blockIdx.x;
  const int wg  = (bid & 7) * 96 + (bid >> 3);
  const int ntl = wg % 12, mtl = wg / 12;
  const int m0 = mtl * 256, n0 = ntl * 256;
  const int seg = n0 >> 9;  // 512-wide segments: 0,1,4 -> x ; 2,3,5 -> h
  const __hip_bfloat16* A = (seg < 2 || seg == 4) ? xb : hb;

  __shared__ __align__(16) char lds[131072];  // 4-slot ring x (A 16K + B 16K)

  const int tid  = threadIdx.x;
  const int lane = tid & 63;
  const int wave = tid >> 6;
  const int wm = wave >> 2, wn = wave & 3;   // 2 x 4 wave grid, 128x64 each

  const char* Ab = (const char*)A  + (size_t)m0 * 1024;  // row = 512*2 B
  const char* Bb = (const char*)Wb + (size_t)n0 * 1024;

  f32x4 acc[8][4];
#pragma unroll
  for (int i = 0; i < 8; ++i)
#pragma unroll
    for (int j = 0; j < 4; ++j) acc[i][j] = (f32x4){0.f, 0.f, 0.f, 0.f};

  // prologue: stage subtiles 0,1,2 (12 loads/thread, subtile-ordered)
#pragma unroll
  for (int s = 0; s < 3; ++s) {
    stage_mat(Ab, lds + s * SLOT_BYTES, s * 64, wave, lane);
    stage_mat(Bb, lds + LDSB_OFF + s * SLOT_BYTES, s * 64, wave, lane);
  }

  // K = 512 = 16 subtiles of 32
  for (int t = 0; t < 13; ++t)
    ktile_step<8, true>(t, Ab, Bb, lds, wave, lane, wm, wn, acc);
  ktile_step<8, false>(13, Ab, Bb, lds, wave, lane, wm, wn, acc);
  ktile_step<4, false>(14, Ab, Bb, lds, wave, lane, wm, wn, acc);
  ktile_step<0, false>(15, Ab, Bb, lds, wave, lane, wm, wn, acc);

  // epilogue: D lane map (verified): col = lane&15, row = (lane>>4)*4 + reg
  const int mbase = m0 + wm * 128 + ((lane >> 4) << 2);
  const int nbase = n0 + wn * 64 + (lane & 15);
#pragma unroll
  for (int fm = 0; fm < 8; ++fm)
#pragma unroll
    for (int fn = 0; fn < 4; ++fn)
#pragma unroll
      for (int r = 0; r < 4; ++r)
        G[(size_t)(mbase + fm * 16 + r) * 3072 + nbase + fn * 16] =
            __float2bfloat16(acc[fm][fn][r]);
}

// ------------------------------ LN + gates ---------------------------------
__device__ __forceinline__ float4 block_red4(float4 v, float* red, int tid) {
#pragma unroll
  for (int off = 32; off; off >>= 1) {
    v.x += __shfl_down(v.x, off);
    v.y += __shfl_down(v.y, off);
    v.z += __shfl_down(v.z, off);
    v.w += __shfl_down(v.w, off);
  }
  __syncthreads();  // protect `red` against previous use
  if ((tid & 63) == 0) {
    const int w = tid >> 6;
    red[w * 4 + 0] = v.x; red[w * 4 + 1] = v.y;
    red[w * 4 + 2] = v.z; red[w * 4 + 3] = v.w;
  }
  __syncthreads();
  return make_float4(red[0] + red[4] + red[8]  + red[12],
                     red[1] + red[5] + red[9]  + red[13],
                     red[2] + red[6] + red[10] + red[14],
                     red[3] + red[7] + red[11] + red[15]);
}

__global__ __launch_bounds__(256) void ln_gate_kernel(
    const __hip_bfloat16* __restrict__ G, const float* __restrict__ h,
    const float* __restrict__ b0, const float* __restrict__ b1,
    const float* __restrict__ b2, const float* __restrict__ b3,
    float* __restrict__ out)
{
  const int row = blockIdx.x;
  const int t   = threadIdx.x;
  const unsigned short* g = (const unsigned short*)(G + (size_t)row * 3072);

  __shared__ float zr[1024];
  __shared__ float red[16];

  float v0[4], v1[4];
  {
    const ushort4 u = *(const ushort4*)(g + 4 * t);
    const float4 b = *(const float4*)(b0 + 4 * t);
    v0[0] = bfraw2f(u.x) + b.x; v0[1] = bfraw2f(u.y) + b.y;
    v0[2] = bfraw2f(u.z) + b.z; v0[3] = bfraw2f(u.w) + b.w;
  }
  {
    const ushort4 u = *(const ushort4*)(g + 1024 + 4 * t);
    const float4 b = *(const float4*)(b1 + 4 * t);
    v1[0] = bfraw2f(u.x) + b.x; v1[1] = bfraw2f(u.y) + b.y;
    v1[2] = bfraw2f(u.z) + b.z; v1[3] = bfraw2f(u.w) + b.w;
  }
  float4 a;
  a.x = v0[0] + v0[1] + v0[2] + v0[3];
  a.y = v0[0]*v0[0] + v0[1]*v0[1] + v0[2]*v0[2] + v0[3]*v0[3];
  a.z = v1[0] + v1[1] + v1[2] + v1[3];
  a.w = v1[0]*v1[0] + v1[1]*v1[1] + v1[2]*v1[2] + v1[3]*v1[3];
  const float4 r01 = block_red4(a, red, t);
  const float mu0 = r01.x * (1.f / 1024.f);
  const float mu1 = r01.z * (1.f / 1024.f);
  const float rs0 = rsqrtf(r01.y * (1.f / 1024.f) - mu0 * mu0 + 1e-5f);
  const float rs1 = rsqrtf(r01.w * (1.f / 1024.f) - mu1 * mu1 + 1e-5f);

#pragma unroll
  for (int k = 0; k < 4; ++k) {
    const float pre = (v0[k] - mu0) * rs0 + (v1[k] - mu1) * rs1;
    zr[4 * t + k] = 1.f / (1.f + __expf(-pre));
  }

  float v2[2], v3[2];
  {
    const ushort2 u = *(const ushort2*)(g + 2048 + 2 * t);
    const float2 b = *(const float2*)(b2 + 2 * t);
    v2[0] = bfraw2f(u.x) + b.x; v2[1] = bfraw2f(u.y) + b.y;
  }
  {
    const ushort2 u = *(const ushort2*)(g + 2560 + 2 * t);
    const float2 b = *(const float2*)(b3 + 2 * t);
    v3[0] = bfraw2f(u.x) + b.x; v3[1] = bfraw2f(u.y) + b.y;
  }
  a.x = v2[0] + v2[1];
  a.y = v2[0]*v2[0] + v2[1]*v2[1];
  a.z = v3[0] + v3[1];
  a.w = v3[0]*v3[0] + v3[1]*v3[1];
  const float4 r23 = block_red4(a, red, t);  // syncs also publish zr[]
  const float mu2 = r23.x * (1.f / 512.f);
  const float mu3 = r23.z * (1.f / 512.f);
  const float rs2 = rsqrtf(r23.y * (1.f / 512.f) - mu2 * mu2 + 1e-5f);
  const float rs3 = rsqrtf(r23.w * (1.f / 512.f) - mu3 * mu3 + 1e-5f);

  const float2 hv = *(const float2*)(h + (size_t)row * 512 + 2 * t);
  float o[2];
#pragma unroll
  for (int k = 0; k < 2; ++k) {
    const int j = 2 * t + k;
    const float ha = (v2[k] - mu2) * rs2;
    const float hb = (v3[k] - mu3) * rs3;
    const float hhat = tanhf(ha + zr[512 + j] * hb);
    const float z = zr[j];
    const float hvk = (k == 0) ? hv.x : hv.y;
    o[k] = (1.f - z) * hvk + z * hhat;
  }
  *(float2*)(out + (size_t)row * 512 + 2 * t) = make_float2(o[0], o[1]);
}

// ------------------------------- launcher ----------------------------------
extern "C" void kernel_launch(void* const* d_in, const int* in_sizes, int n_in,
                              void* d_out, int out_size, void* d_ws, size_t ws_size,
                              hipStream_t stream) {
  (void)in_sizes; (void)n_in; (void)out_size; (void)ws_size;
  const float* x      = (const float*)d_in[0];
  const float* h      = (const float*)d_in[1];
  const float* W_i2h  = (const float*)d_in[2];
  const float* b_i2h  = (const float*)d_in[3];
  const float* W_h2h  = (const float*)d_in[4];
  const float* b_h2h  = (const float*)d_in[5];
  const float* W_hatW = (const float*)d_in[6];
  const float* b_hatW = (const float*)d_in[7];
  const float* W_hatU = (const float*)d_in[8];
  const float* b_hatU = (const float*)d_in[9];
  float* out = (float*)d_out;
  __hip_bfloat16* ws = (__hip_bfloat16*)d_ws;

  convert_kernel<<<17920, 256, 0, stream>>>(x, h, W_i2h, W_h2h, W_hatW, W_hatU, ws);
  gemm_kernel<<<768, 512, 0, stream>>>(ws + XB_OFF, ws + HB_OFF,
                                       ws + WB_OFF, ws + GB_OFF);
  ln_gate_kernel<<<16384, 256, 0, stream>>>(ws + GB_OFF, h, b_i2h, b_h2h,
                                            b_hatW, b_hatU, out);
}

// Round 4
// 135.791 us; speedup vs baseline: 1.0884x; 1.0018x over previous
//
#include <hip/hip_runtime.h>
#include <hip/hip_bf16.h>

// ---------------------------------------------------------------------------
// LayerNormGRUCell: B=16384, I=H=512
//   G = [x@W_i2h.T | h@W_h2h.T | x@W_hatW.T | h@W_hatU.T]  (16384 x 3072)
//   then per-row: LN segments + gates + tanh + lerp -> h_t (16384 x 512 fp32)
// ws layout (bf16 elements):
//   xb   @ 0         (16384*512)
//   hb   @ 8388608   (16384*512)
//   Wcat @ 16777216  (3072*512)   rows: [W_i2h;W_h2h;W_hatW;W_hatU]
//   Gb   @ 18350080  (16384*3072)
// ---------------------------------------------------------------------------

using f32x4 = __attribute__((ext_vector_type(4))) float;
using s16x8 = __attribute__((ext_vector_type(8))) short;

#define XB_OFF   0ull
#define HB_OFF   8388608ull
#define WB_OFF   16777216ull
#define GB_OFF   18350080ull

// vec4 segment boundaries for the convert kernel
#define CV_X_END   2097152ull
#define CV_H_END   4194304ull
#define CV_W0_END  4325376ull
#define CV_W1_END  4456448ull
#define CV_W2_END  4521984ull
#define CV_W3_END  4587520ull

__device__ __forceinline__ void async_load16(const void* g, void* l) {
  __builtin_amdgcn_global_load_lds(
      (const __attribute__((address_space(1))) unsigned int*)g,
      (__attribute__((address_space(3))) unsigned int*)l, 16, 0, 0);
}

__device__ __forceinline__ float bfraw2f(unsigned short u) {
  union { unsigned int i; float f; } c;
  c.i = ((unsigned int)u) << 16;
  return c.f;
}

// -------------------------- fp32 -> bf16 conversion ------------------------
__global__ __launch_bounds__(256) void convert_kernel(
    const float* __restrict__ x, const float* __restrict__ h,
    const float* __restrict__ w0, const float* __restrict__ w1,
    const float* __restrict__ w2, const float* __restrict__ w3,
    __hip_bfloat16* __restrict__ ws)
{
  const size_t i = (size_t)blockIdx.x * 256 + threadIdx.x;  // vec4 index
  const float* src;
  __hip_bfloat16* dst;
  size_t o;
  if (i < CV_X_END)        { src = x;  dst = ws + XB_OFF;            o = i; }
  else if (i < CV_H_END)   { src = h;  dst = ws + HB_OFF;            o = i - CV_X_END; }
  else if (i < CV_W0_END)  { src = w0; dst = ws + WB_OFF;            o = i - CV_H_END; }
  else if (i < CV_W1_END)  { src = w1; dst = ws + WB_OFF + 524288;   o = i - CV_W0_END; }
  else if (i < CV_W2_END)  { src = w2; dst = ws + WB_OFF + 1048576;  o = i - CV_W1_END; }
  else                     { src = w3; dst = ws + WB_OFF + 1310720;  o = i - CV_W2_END; }
  const float4 v = *(const float4*)(src + 4 * o);
  __hip_bfloat16 t4[4] = {__float2bfloat16(v.x), __float2bfloat16(v.y),
                          __float2bfloat16(v.z), __float2bfloat16(v.w)};
  *(uint2*)(dst + 4 * o) = *(const uint2*)t4;
}

// -------------------------------- GEMM -------------------------------------
// 256x256 tile, BK=32, 8 waves (2Mx4N), 4-slot LDS ring (128 KiB), counted
// vmcnt pipeline (T3+T4), XOR-swizzled LDS (T2), setprio around MFMA (T5),
// bijective XCD block swizzle (T1), m201-style barrier-paired phases (T3).
// C[m,n] = sum_k A[m,k]*W[n,k].
//
// LDS slot layout (per matrix): [256 rows][32 bf16 = 64 B], physical column
// byte cb holds global k-byte (cb ^ swz(row)), swz(row) = ((row>>1)&3)<<4.
// global_load_lds writes linearly; the source global address is pre-swizzled
// so LDS(row,cb) = G(row, cb ^ swz(row)); ds_read applies the same XOR.

#define SLOT_BYTES 16384   // 256*32*2
#define LDSB_OFF   65536   // 4 A slots

__device__ __forceinline__ void stage_mat(const char* base, char* slot,
                                          int koff, int wave, int lane) {
#pragma unroll
  for (int i = 0; i < 2; ++i) {
    const int c = wave * 2 + i;                       // 16-row chunk, 1024 B
    const int row = c * 16 + (lane >> 2);
    const int colb = ((lane & 3) * 16) ^ (((lane >> 3) & 3) << 4);  // pre-swz
    async_load16(base + (size_t)row * 1024 + koff + colb,
                 slot + c * 1024 + lane * 16);
  }
}

template <int VM>
__device__ __forceinline__ void wait_vm() {
  if constexpr (VM == 8)      asm volatile("s_waitcnt vmcnt(8)" ::: "memory");
  else if constexpr (VM == 4) asm volatile("s_waitcnt vmcnt(4)" ::: "memory");
  else                        asm volatile("s_waitcnt vmcnt(0)" ::: "memory");
}

template <int VM, bool STAGE>
__device__ __forceinline__ void ktile_step(
    int t, const char* Ab, const char* Bb, char* lds,
    int wave, int lane, int wm, int wn, f32x4 (&acc)[8][4])
{
  wait_vm<VM>();                       // counted: subtiles t+1,t+2 stay in flight
  __builtin_amdgcn_s_barrier();        // all threads drained their subtile-t loads
  char* slotA = lds + (t & 3) * SLOT_BYTES;
  char* slotB = lds + LDSB_OFF + (t & 3) * SLOT_BYTES;
  char* stA   = lds + ((t + 3) & 3) * SLOT_BYTES;            // == slot (t-1)&3:
  char* stB   = lds + LDSB_OFF + ((t + 3) & 3) * SLOT_BYTES; // reads done pre-barrier
  const int lk = (lane >> 4) * 16;
  const int lr = lane & 15;

  // ---- phase Q0: read b0-3, a0-3 | stage A(t+3) | BAR | MFMA ----
  s16x8 a[4], b[4];
#pragma unroll
  for (int fn = 0; fn < 4; ++fn) {
    const int r = wn * 64 + fn * 16 + lr;
    b[fn] = *(const s16x8*)(slotB + r * 64 + (lk ^ (((r >> 1) & 3) << 4)));
  }
#pragma unroll
  for (int fm = 0; fm < 4; ++fm) {
    const int r = wm * 128 + fm * 16 + lr;
    a[fm] = *(const s16x8*)(slotA + r * 64 + (lk ^ (((r >> 1) & 3) << 4)));
  }
  if (STAGE) stage_mat(Ab, stA, (t + 3) * 64, wave, lane);
  __builtin_amdgcn_s_barrier();
  asm volatile("s_waitcnt lgkmcnt(0)" ::: "memory");
  __builtin_amdgcn_sched_barrier(0);   // rule 18: keep MFMA below the wait
  __builtin_amdgcn_s_setprio(1);
#pragma unroll
  for (int fm = 0; fm < 4; ++fm)
#pragma unroll
    for (int fn = 0; fn < 4; ++fn)
      acc[fm][fn] = __builtin_amdgcn_mfma_f32_16x16x32_bf16(a[fm], b[fn], acc[fm][fn], 0, 0, 0);
  __builtin_amdgcn_s_setprio(0);
  __builtin_amdgcn_s_barrier();

  // ---- phase Q1: read a4-7 | stage B(t+3) | BAR | MFMA ----
  s16x8 a2[4];
#pragma unroll
  for (int fm = 0; fm < 4; ++fm) {
    const int r = wm * 128 + 64 + fm * 16 + lr;
    a2[fm] = *(const s16x8*)(slotA + r * 64 + (lk ^ (((r >> 1) & 3) << 4)));
  }
  if (STAGE) stage_mat(Bb, stB, (t + 3) * 64, wave, lane);
  __builtin_amdgcn_s_barrier();
  asm volatile("s_waitcnt lgkmcnt(0)" ::: "memory");
  __builtin_amdgcn_sched_barrier(0);
  __builtin_amdgcn_s_setprio(1);
#pragma unroll
  for (int fm = 0; fm < 4; ++fm)
#pragma unroll
    for (int fn = 0; fn < 4; ++fn)
      acc[4 + fm][fn] = __builtin_amdgcn_mfma_f32_16x16x32_bf16(a2[fm], b[fn], acc[4 + fm][fn], 0, 0, 0);
  __builtin_amdgcn_s_setprio(0);
  // closing barrier = next ktile's entry barrier
}

__global__ __launch_bounds__(512, 2) void gemm_kernel(
    const __hip_bfloat16* __restrict__ xb,
    const __hip_bfloat16* __restrict__ hb,
    const __hip_bfloat16* __restrict__ Wb,
    __hip_bfloat16* __restrict__ G)
{
  // T1: bijective XCD swizzle; nwg=768, 768%8==0, chunk=96 wgs/XCD.
  const int bid = blockIdx.x;
  const int wg  = (bid & 7) * 96 + (bid >> 3);
  const int ntl = wg % 12, mtl = wg / 12;
  const int m0 = mtl * 256, n0 = ntl * 256;
  const int seg = n0 >> 9;  // 512-wide segments: 0,1,4 -> x ; 2,3,5 -> h
  const __hip_bfloat16* A = (seg < 2 || seg == 4) ? xb : hb;

  __shared__ __align__(16) char lds[131072];  // 4-slot ring x (A 16K + B 16K)

  const int tid  = threadIdx.x;
  const int lane = tid & 63;
  const int wave = tid >> 6;
  const int wm = wave >> 2, wn = wave & 3;   // 2 x 4 wave grid, 128x64 each

  const char* Ab = (const char*)A  + (size_t)m0 * 1024;  // row = 512*2 B
  const char* Bb = (const char*)Wb + (size_t)n0 * 1024;

  f32x4 acc[8][4];
#pragma unroll
  for (int i = 0; i < 8; ++i)
#pragma unroll
    for (int j = 0; j < 4; ++j) acc[i][j] = (f32x4){0.f, 0.f, 0.f, 0.f};

  // prologue: stage subtiles 0,1,2 (12 loads/thread, subtile-ordered)
#pragma unroll
  for (int s = 0; s < 3; ++s) {
    stage_mat(Ab, lds + s * SLOT_BYTES, s * 64, wave, lane);
    stage_mat(Bb, lds + LDSB_OFF + s * SLOT_BYTES, s * 64, wave, lane);
  }

  // K = 512 = 16 subtiles of 32
  for (int t = 0; t < 13; ++t)
    ktile_step<8, true>(t, Ab, Bb, lds, wave, lane, wm, wn, acc);
  ktile_step<8, false>(13, Ab, Bb, lds, wave, lane, wm, wn, acc);
  ktile_step<4, false>(14, Ab, Bb, lds, wave, lane, wm, wn, acc);
  ktile_step<0, false>(15, Ab, Bb, lds, wave, lane, wm, wn, acc);

  // epilogue: D lane map (verified): col = lane&15, row = (lane>>4)*4 + reg
  const int mbase = m0 + wm * 128 + ((lane >> 4) << 2);
  const int nbase = n0 + wn * 64 + (lane & 15);
#pragma unroll
  for (int fm = 0; fm < 8; ++fm)
#pragma unroll
    for (int fn = 0; fn < 4; ++fn)
#pragma unroll
      for (int r = 0; r < 4; ++r)
        G[(size_t)(mbase + fm * 16 + r) * 3072 + nbase + fn * 16] =
            __float2bfloat16(acc[fm][fn][r]);
}

// ------------------------------ LN + gates ---------------------------------
__device__ __forceinline__ float4 block_red4(float4 v, float* red, int tid) {
#pragma unroll
  for (int off = 32; off; off >>= 1) {
    v.x += __shfl_down(v.x, off);
    v.y += __shfl_down(v.y, off);
    v.z += __shfl_down(v.z, off);
    v.w += __shfl_down(v.w, off);
  }
  __syncthreads();  // protect `red` against previous use
  if ((tid & 63) == 0) {
    const int w = tid >> 6;
    red[w * 4 + 0] = v.x; red[w * 4 + 1] = v.y;
    red[w * 4 + 2] = v.z; red[w * 4 + 3] = v.w;
  }
  __syncthreads();
  return make_float4(red[0] + red[4] + red[8]  + red[12],
                     red[1] + red[5] + red[9]  + red[13],
                     red[2] + red[6] + red[10] + red[14],
                     red[3] + red[7] + red[11] + red[15]);
}

__global__ __launch_bounds__(256) void ln_gate_kernel(
    const __hip_bfloat16* __restrict__ G, const float* __restrict__ h,
    const float* __restrict__ b0, const float* __restrict__ b1,
    const float* __restrict__ b2, const float* __restrict__ b3,
    float* __restrict__ out)
{
  const int row = blockIdx.x;
  const int t   = threadIdx.x;
  const unsigned short* g = (const unsigned short*)(G + (size_t)row * 3072);

  __shared__ float zr[1024];
  __shared__ float red[16];

  float v0[4], v1[4];
  {
    const ushort4 u = *(const ushort4*)(g + 4 * t);
    const float4 b = *(const float4*)(b0 + 4 * t);
    v0[0] = bfraw2f(u.x) + b.x; v0[1] = bfraw2f(u.y) + b.y;
    v0[2] = bfraw2f(u.z) + b.z; v0[3] = bfraw2f(u.w) + b.w;
  }
  {
    const ushort4 u = *(const ushort4*)(g + 1024 + 4 * t);
    const float4 b = *(const float4*)(b1 + 4 * t);
    v1[0] = bfraw2f(u.x) + b.x; v1[1] = bfraw2f(u.y) + b.y;
    v1[2] = bfraw2f(u.z) + b.z; v1[3] = bfraw2f(u.w) + b.w;
  }
  float4 a;
  a.x = v0[0] + v0[1] + v0[2] + v0[3];
  a.y = v0[0]*v0[0] + v0[1]*v0[1] + v0[2]*v0[2] + v0[3]*v0[3];
  a.z = v1[0] + v1[1] + v1[2] + v1[3];
  a.w = v1[0]*v1[0] + v1[1]*v1[1] + v1[2]*v1[2] + v1[3]*v1[3];
  const float4 r01 = block_red4(a, red, t);
  const float mu0 = r01.x * (1.f / 1024.f);
  const float mu1 = r01.z * (1.f / 1024.f);
  const float rs0 = rsqrtf(r01.y * (1.f / 1024.f) - mu0 * mu0 + 1e-5f);
  const float rs1 = rsqrtf(r01.w * (1.f / 1024.f) - mu1 * mu1 + 1e-5f);

#pragma unroll
  for (int k = 0; k < 4; ++k) {
    const float pre = (v0[k] - mu0) * rs0 + (v1[k] - mu1) * rs1;
    zr[4 * t + k] = 1.f / (1.f + __expf(-pre));
  }

  float v2[2], v3[2];
  {
    const ushort2 u = *(const ushort2*)(g + 2048 + 2 * t);
    const float2 b = *(const float2*)(b2 + 2 * t);
    v2[0] = bfraw2f(u.x) + b.x; v2[1] = bfraw2f(u.y) + b.y;
  }
  {
    const ushort2 u = *(const ushort2*)(g + 2560 + 2 * t);
    const float2 b = *(const float2*)(b3 + 2 * t);
    v3[0] = bfraw2f(u.x) + b.x; v3[1] = bfraw2f(u.y) + b.y;
  }
  a.x = v2[0] + v2[1];
  a.y = v2[0]*v2[0] + v2[1]*v2[1];
  a.z = v3[0] + v3[1];
  a.w = v3[0]*v3[0] + v3[1]*v3[1];
  const float4 r23 = block_red4(a, red, t);  // syncs also publish zr[]
  const float mu2 = r23.x * (1.f / 512.f);
  const float mu3 = r23.z * (1.f / 512.f);
  const float rs2 = rsqrtf(r23.y * (1.f / 512.f) - mu2 * mu2 + 1e-5f);
  const float rs3 = rsqrtf(r23.w * (1.f / 512.f) - mu3 * mu3 + 1e-5f);

  const float2 hv = *(const float2*)(h + (size_t)row * 512 + 2 * t);
  float o[2];
#pragma unroll
  for (int k = 0; k < 2; ++k) {
    const int j = 2 * t + k;
    const float ha = (v2[k] - mu2) * rs2;
    const float hb = (v3[k] - mu3) * rs3;
    const float hhat = tanhf(ha + zr[512 + j] * hb);
    const float z = zr[j];
    const float hvk = (k == 0) ? hv.x : hv.y;
    o[k] = (1.f - z) * hvk + z * hhat;
  }
  *(float2*)(out + (size_t)row * 512 + 2 * t) = make_float2(o[0], o[1]);
}

// ------------------------------- launcher ----------------------------------
extern "C" void kernel_launch(void* const* d_in, const int* in_sizes, int n_in,
                              void* d_out, int out_size, void* d_ws, size_t ws_size,
                              hipStream_t stream) {
  (void)in_sizes; (void)n_in; (void)out_size; (void)ws_size;
  const float* x      = (const float*)d_in[0];
  const float* h      = (const float*)d_in[1];
  const float* W_i2h  = (const float*)d_in[2];
  const float* b_i2h  = (const float*)d_in[3];
  const float* W_h2h  = (const float*)d_in[4];
  const float* b_h2h  = (const float*)d_in[5];
  const float* W_hatW = (const float*)d_in[6];
  const float* b_hatW = (const float*)d_in[7];
  const float* W_hatU = (const float*)d_in[8];
  const float* b_hatU = (const float*)d_in[9];
  float* out = (float*)d_out;
  __hip_bfloat16* ws = (__hip_bfloat16*)d_ws;

  convert_kernel<<<17920, 256, 0, stream>>>(x, h, W_i2h, W_h2h, W_hatW, W_hatU, ws);
  gemm_kernel<<<768, 512, 0, stream>>>(ws + XB_OFF, ws + HB_OFF,
                                       ws + WB_OFF, ws + GB_OFF);
  ln_gate_kernel<<<16384, 256, 0, stream>>>(ws + GB_OFF, h, b_i2h, b_h2h,
                                            b_hatW, b_hatU, out);
}

// Round 5
// 134.902 us; speedup vs baseline: 1.0956x; 1.0066x over previous
//
#include <hip/hip_runtime.h>
#include <hip/hip_bf16.h>

// ---------------------------------------------------------------------------
// LayerNormGRUCell: B=16384, I=H=512
//   G = [x@W_i2h.T | h@W_h2h.T | x@W_hatW.T | h@W_hatU.T]  (16384 x 3072)
//   then per-row: LN segments + gates + tanh + lerp -> h_t (16384 x 512 fp32)
// ws layout (bf16 elements):
//   xb   @ 0         (16384*512)
//   hb   @ 8388608   (16384*512)
//   Wcat @ 16777216  (3072*512)   rows: [W_i2h;W_h2h;W_hatW;W_hatU]
//   Gb   @ 18350080  (16384*3072)
// ---------------------------------------------------------------------------

using f32x4 = __attribute__((ext_vector_type(4))) float;
using s16x8 = __attribute__((ext_vector_type(8))) short;

#define XB_OFF   0ull
#define HB_OFF   8388608ull
#define WB_OFF   16777216ull
#define GB_OFF   18350080ull

// vec4 segment boundaries for the convert kernel
#define CV_X_END   2097152ull
#define CV_H_END   4194304ull
#define CV_W0_END  4325376ull
#define CV_W1_END  4456448ull
#define CV_W2_END  4521984ull
#define CV_W3_END  4587520ull

__device__ __forceinline__ void async_load16(const void* g, void* l) {
  __builtin_amdgcn_global_load_lds(
      (const __attribute__((address_space(1))) unsigned int*)g,
      (__attribute__((address_space(3))) unsigned int*)l, 16, 0, 0);
}

__device__ __forceinline__ float bfraw2f(unsigned short u) {
  union { unsigned int i; float f; } c;
  c.i = ((unsigned int)u) << 16;
  return c.f;
}

// -------------------------- fp32 -> bf16 conversion ------------------------
__global__ __launch_bounds__(256) void convert_kernel(
    const float* __restrict__ x, const float* __restrict__ h,
    const float* __restrict__ w0, const float* __restrict__ w1,
    const float* __restrict__ w2, const float* __restrict__ w3,
    __hip_bfloat16* __restrict__ ws)
{
  const size_t i = (size_t)blockIdx.x * 256 + threadIdx.x;  // vec4 index
  const float* src;
  __hip_bfloat16* dst;
  size_t o;
  if (i < CV_X_END)        { src = x;  dst = ws + XB_OFF;            o = i; }
  else if (i < CV_H_END)   { src = h;  dst = ws + HB_OFF;            o = i - CV_X_END; }
  else if (i < CV_W0_END)  { src = w0; dst = ws + WB_OFF;            o = i - CV_H_END; }
  else if (i < CV_W1_END)  { src = w1; dst = ws + WB_OFF + 524288;   o = i - CV_W0_END; }
  else if (i < CV_W2_END)  { src = w2; dst = ws + WB_OFF + 1048576;  o = i - CV_W1_END; }
  else                     { src = w3; dst = ws + WB_OFF + 1310720;  o = i - CV_W2_END; }
  const float4 v = *(const float4*)(src + 4 * o);
  __hip_bfloat16 t4[4] = {__float2bfloat16(v.x), __float2bfloat16(v.y),
                          __float2bfloat16(v.z), __float2bfloat16(v.w)};
  *(uint2*)(dst + 4 * o) = *(const uint2*)t4;
}

// -------------------------------- GEMM -------------------------------------
// 256x256 tile, BK=32, 8 waves (2Mx4N), 4-slot LDS ring (128 KiB).
// Register-double-buffered fragment pipeline: each phase issues the NEXT
// phase's ds_reads, then runs MFMA on the previous set -> LDS service
// overlaps matrix-pipe execution (counted lgkmcnt emitted by the compiler).
// One barrier per ktile (slot WAR). vmcnt(4) at entry confirms slots t AND
// t+1 so the 1-phase read-lookahead across the ktile boundary is race-free.
// T1 XCD swizzle, T2 XOR-swizzled LDS, T5 setprio. Full K-loop unroll (SSA
// ping-pong regs, no v_movs).
//
// LDS slot layout (per matrix): [256 rows][32 bf16 = 64 B], physical column
// byte cb holds global k-byte (cb ^ swz(row)), swz(row) = ((row>>1)&3)<<4.
// global_load_lds writes linearly; source global address pre-swizzled;
// ds_read applies the same XOR (rule 21).

#define SLOT_BYTES 16384   // 256*32*2
#define LDSB_OFF   65536   // 4 A slots

__device__ __forceinline__ void stage_mat(const char* base, char* slot,
                                          int koff, int wave, int lane) {
#pragma unroll
  for (int i = 0; i < 2; ++i) {
    const int c = wave * 2 + i;                       // 16-row chunk, 1024 B
    const int row = c * 16 + (lane >> 2);
    const int colb = ((lane & 3) * 16) ^ (((lane >> 3) & 3) << 4);  // pre-swz
    async_load16(base + (size_t)row * 1024 + koff + colb,
                 slot + c * 1024 + lane * 16);
  }
}

__global__ __launch_bounds__(512, 2) void gemm_kernel(
    const __hip_bfloat16* __restrict__ xb,
    const __hip_bfloat16* __restrict__ hb,
    const __hip_bfloat16* __restrict__ Wb,
    __hip_bfloat16* __restrict__ G)
{
  // T1: bijective XCD swizzle; nwg=768, 768%8==0, chunk=96 wgs/XCD.
  const int bid = blockIdx.x;
  const int wg  = (bid & 7) * 96 + (bid >> 3);
  const int ntl = wg % 12, mtl = wg / 12;
  const int m0 = mtl * 256, n0 = ntl * 256;
  const int seg = n0 >> 9;  // 512-wide segments: 0,1,4 -> x ; 2,3,5 -> h
  const __hip_bfloat16* A = (seg < 2 || seg == 4) ? xb : hb;

  __shared__ __align__(16) char lds[131072];  // 4-slot ring x (A 16K + B 16K)

  const int tid  = threadIdx.x;
  const int lane = tid & 63;
  const int wave = tid >> 6;
  const int wm = wave >> 2, wn = wave & 3;   // 2 x 4 wave grid, 128x64 each

  const char* Ab = (const char*)A  + (size_t)m0 * 1024;  // row = 512*2 B
  const char* Bb = (const char*)Wb + (size_t)n0 * 1024;

  const int lk = (lane >> 4) * 16;
  const int lr = lane & 15;

  // fragment readers (slot index by ktile t)
  auto rdB = [&](int fn, int t) {
    const int r = wn * 64 + fn * 16 + lr;
    return *(const s16x8*)(lds + LDSB_OFF + (size_t)(t & 3) * SLOT_BYTES +
                           r * 64 + (lk ^ (((r >> 1) & 3) << 4)));
  };
  auto rdA = [&](int fm, int half, int t) {
    const int r = wm * 128 + half * 64 + fm * 16 + lr;
    return *(const s16x8*)(lds + (size_t)(t & 3) * SLOT_BYTES +
                           r * 64 + (lk ^ (((r >> 1) & 3) << 4)));
  };

  f32x4 acc[8][4];
#pragma unroll
  for (int i = 0; i < 8; ++i)
#pragma unroll
    for (int j = 0; j < 4; ++j) acc[i][j] = (f32x4){0.f, 0.f, 0.f, 0.f};

  // prologue: stage slots 0,1,2 (12 loads/thread, slot-ordered)
#pragma unroll
  for (int s = 0; s < 3; ++s) {
    stage_mat(Ab, lds + s * SLOT_BYTES, s * 64, wave, lane);
    stage_mat(Bb, lds + LDSB_OFF + s * SLOT_BYTES, s * 64, wave, lane);
  }
  asm volatile("s_waitcnt vmcnt(4)" ::: "memory");   // slots 0,1 resident
  __builtin_amdgcn_s_barrier();

  s16x8 bA[4], a0v[4], a1v[4];
#pragma unroll
  for (int fn = 0; fn < 4; ++fn) bA[fn] = rdB(fn, 0);
#pragma unroll
  for (int fm = 0; fm < 4; ++fm) a0v[fm] = rdA(fm, 0, 0);

  // K = 512 = 16 ktiles of 32, fully unrolled
#pragma unroll
  for (int t = 0; t < 16; ++t) {
    if (t > 0) {
      // confirm slots t and t+1 resident (lookahead reads hit t+1)
      if (t <= 13)      asm volatile("s_waitcnt vmcnt(4)" ::: "memory");
      else if (t == 14) asm volatile("s_waitcnt vmcnt(0)" ::: "memory");
      __builtin_amdgcn_s_barrier();    // all waves done reading slot t-1
    }

    // ---- phase Q0: issue a4-7(t) | stage A(t+3) | MFMA on (bA, a0v) ----
#pragma unroll
    for (int fm = 0; fm < 4; ++fm) a1v[fm] = rdA(fm, 1, t);
    if (t < 13) stage_mat(Ab, lds + ((t + 3) & 3) * SLOT_BYTES,
                          (t + 3) * 64, wave, lane);
    __builtin_amdgcn_s_setprio(1);
#pragma unroll
    for (int fm = 0; fm < 4; ++fm)
#pragma unroll
      for (int fn = 0; fn < 4; ++fn)
        acc[fm][fn] = __builtin_amdgcn_mfma_f32_16x16x32_bf16(
            a0v[fm], bA[fn], acc[fm][fn], 0, 0, 0);
    __builtin_amdgcn_s_setprio(0);

    // ---- phase Q1: issue b,a0-3(t+1) | stage B(t+3) | MFMA on (bA, a1v) --
    s16x8 bN[4], aN[4];
    if (t < 15) {
#pragma unroll
      for (int fn = 0; fn < 4; ++fn) bN[fn] = rdB(fn, t + 1);
#pragma unroll
      for (int fm = 0; fm < 4; ++fm) aN[fm] = rdA(fm, 0, t + 1);
    }
    if (t < 13) stage_mat(Bb, lds + LDSB_OFF + ((t + 3) & 3) * SLOT_BYTES,
                          (t + 3) * 64, wave, lane);
    __builtin_amdgcn_s_setprio(1);
#pragma unroll
    for (int fm = 0; fm < 4; ++fm)
#pragma unroll
      for (int fn = 0; fn < 4; ++fn)
        acc[4 + fm][fn] = __builtin_amdgcn_mfma_f32_16x16x32_bf16(
            a1v[fm], bA[fn], acc[4 + fm][fn], 0, 0, 0);
    __builtin_amdgcn_s_setprio(0);

    if (t < 15) {
#pragma unroll
      for (int i = 0; i < 4; ++i) { bA[i] = bN[i]; a0v[i] = aN[i]; }
    }
  }

  // epilogue: D lane map (verified): col = lane&15, row = (lane>>4)*4 + reg
  const int mbase = m0 + wm * 128 + ((lane >> 4) << 2);
  const int nbase = n0 + wn * 64 + (lane & 15);
#pragma unroll
  for (int fm = 0; fm < 8; ++fm)
#pragma unroll
    for (int fn = 0; fn < 4; ++fn)
#pragma unroll
      for (int r = 0; r < 4; ++r)
        G[(size_t)(mbase + fm * 16 + r) * 3072 + nbase + fn * 16] =
            __float2bfloat16(acc[fm][fn][r]);
}

// ------------------------------ LN + gates ---------------------------------
__device__ __forceinline__ float4 block_red4(float4 v, float* red, int tid) {
#pragma unroll
  for (int off = 32; off; off >>= 1) {
    v.x += __shfl_down(v.x, off);
    v.y += __shfl_down(v.y, off);
    v.z += __shfl_down(v.z, off);
    v.w += __shfl_down(v.w, off);
  }
  __syncthreads();  // protect `red` against previous use
  if ((tid & 63) == 0) {
    const int w = tid >> 6;
    red[w * 4 + 0] = v.x; red[w * 4 + 1] = v.y;
    red[w * 4 + 2] = v.z; red[w * 4 + 3] = v.w;
  }
  __syncthreads();
  return make_float4(red[0] + red[4] + red[8]  + red[12],
                     red[1] + red[5] + red[9]  + red[13],
                     red[2] + red[6] + red[10] + red[14],
                     red[3] + red[7] + red[11] + red[15]);
}

__global__ __launch_bounds__(256) void ln_gate_kernel(
    const __hip_bfloat16* __restrict__ G, const float* __restrict__ h,
    const float* __restrict__ b0, const float* __restrict__ b1,
    const float* __restrict__ b2, const float* __restrict__ b3,
    float* __restrict__ out)
{
  const int row = blockIdx.x;
  const int t   = threadIdx.x;
  const unsigned short* g = (const unsigned short*)(G + (size_t)row * 3072);

  __shared__ float zr[1024];
  __shared__ float red[16];

  float v0[4], v1[4];
  {
    const ushort4 u = *(const ushort4*)(g + 4 * t);
    const float4 b = *(const float4*)(b0 + 4 * t);
    v0[0] = bfraw2f(u.x) + b.x; v0[1] = bfraw2f(u.y) + b.y;
    v0[2] = bfraw2f(u.z) + b.z; v0[3] = bfraw2f(u.w) + b.w;
  }
  {
    const ushort4 u = *(const ushort4*)(g + 1024 + 4 * t);
    const float4 b = *(const float4*)(b1 + 4 * t);
    v1[0] = bfraw2f(u.x) + b.x; v1[1] = bfraw2f(u.y) + b.y;
    v1[2] = bfraw2f(u.z) + b.z; v1[3] = bfraw2f(u.w) + b.w;
  }
  float4 a;
  a.x = v0[0] + v0[1] + v0[2] + v0[3];
  a.y = v0[0]*v0[0] + v0[1]*v0[1] + v0[2]*v0[2] + v0[3]*v0[3];
  a.z = v1[0] + v1[1] + v1[2] + v1[3];
  a.w = v1[0]*v1[0] + v1[1]*v1[1] + v1[2]*v1[2] + v1[3]*v1[3];
  const float4 r01 = block_red4(a, red, t);
  const float mu0 = r01.x * (1.f / 1024.f);
  const float mu1 = r01.z * (1.f / 1024.f);
  const float rs0 = rsqrtf(r01.y * (1.f / 1024.f) - mu0 * mu0 + 1e-5f);
  const float rs1 = rsqrtf(r01.w * (1.f / 1024.f) - mu1 * mu1 + 1e-5f);

#pragma unroll
  for (int k = 0; k < 4; ++k) {
    const float pre = (v0[k] - mu0) * rs0 + (v1[k] - mu1) * rs1;
    zr[4 * t + k] = 1.f / (1.f + __expf(-pre));
  }

  float v2[2], v3[2];
  {
    const ushort2 u = *(const ushort2*)(g + 2048 + 2 * t);
    const float2 b = *(const float2*)(b2 + 2 * t);
    v2[0] = bfraw2f(u.x) + b.x; v2[1] = bfraw2f(u.y) + b.y;
  }
  {
    const ushort2 u = *(const ushort2*)(g + 2560 + 2 * t);
    const float2 b = *(const float2*)(b3 + 2 * t);
    v3[0] = bfraw2f(u.x) + b.x; v3[1] = bfraw2f(u.y) + b.y;
  }
  a.x = v2[0] + v2[1];
  a.y = v2[0]*v2[0] + v2[1]*v2[1];
  a.z = v3[0] + v3[1];
  a.w = v3[0]*v3[0] + v3[1]*v3[1];
  const float4 r23 = block_red4(a, red, t);  // syncs also publish zr[]
  const float mu2 = r23.x * (1.f / 512.f);
  const float mu3 = r23.z * (1.f / 512.f);
  const float rs2 = rsqrtf(r23.y * (1.f / 512.f) - mu2 * mu2 + 1e-5f);
  const float rs3 = rsqrtf(r23.w * (1.f / 512.f) - mu3 * mu3 + 1e-5f);

  const float2 hv = *(const float2*)(h + (size_t)row * 512 + 2 * t);
  float o[2];
#pragma unroll
  for (int k = 0; k < 2; ++k) {
    const int j = 2 * t + k;
    const float ha = (v2[k] - mu2) * rs2;
    const float hb = (v3[k] - mu3) * rs3;
    const float hhat = tanhf(ha + zr[512 + j] * hb);
    const float z = zr[j];
    const float hvk = (k == 0) ? hv.x : hv.y;
    o[k] = (1.f - z) * hvk + z * hhat;
  }
  *(float2*)(out + (size_t)row * 512 + 2 * t) = make_float2(o[0], o[1]);
}

// ------------------------------- launcher ----------------------------------
extern "C" void kernel_launch(void* const* d_in, const int* in_sizes, int n_in,
                              void* d_out, int out_size, void* d_ws, size_t ws_size,
                              hipStream_t stream) {
  (void)in_sizes; (void)n_in; (void)out_size; (void)ws_size;
  const float* x      = (const float*)d_in[0];
  const float* h      = (const float*)d_in[1];
  const float* W_i2h  = (const float*)d_in[2];
  const float* b_i2h  = (const float*)d_in[3];
  const float* W_h2h  = (const float*)d_in[4];
  const float* b_h2h  = (const float*)d_in[5];
  const float* W_hatW = (const float*)d_in[6];
  const float* b_hatW = (const float*)d_in[7];
  const float* W_hatU = (const float*)d_in[8];
  const float* b_hatU = (const float*)d_in[9];
  float* out = (float*)d_out;
  __hip_bfloat16* ws = (__hip_bfloat16*)d_ws;

  convert_kernel<<<17920, 256, 0, stream>>>(x, h, W_i2h, W_h2h, W_hatW, W_hatU, ws);
  gemm_kernel<<<768, 512, 0, stream>>>(ws + XB_OFF, ws + HB_OFF,
                                       ws + WB_OFF, ws + GB_OFF);
  ln_gate_kernel<<<16384, 256, 0, stream>>>(ws + GB_OFF, h, b_i2h, b_h2h,
                                            b_hatW, b_hatU, out);
}